// Round 12
// baseline (350.009 us; speedup 1.0000x reference)
//
#include <hip/hip_runtime.h>

#define T_DIM 2048
#define B_DIM 16
#define E_DIM 1024
#define CD    1024
#define NH    16
#define KSZ   31
#define M_DIM 32768
#define SLICE 131072            // 2048*64 elements per (b,h) slice
#define BSTRIDE 2097152         // 2048*1024 = 16*SLICE

typedef unsigned int u32;
typedef unsigned short u16;
typedef __attribute__((ext_vector_type(8))) __bf16 bf16x8;
typedef __attribute__((ext_vector_type(4))) float f32x4;
typedef __attribute__((ext_vector_type(4))) float fvec4;
typedef __attribute__((ext_vector_type(8))) unsigned short us8;
typedef __attribute__((ext_vector_type(4))) unsigned short us4;
typedef __attribute__((ext_vector_type(4))) unsigned int ui4;

__device__ __forceinline__ float bf2f(u16 u) {
  union { float f; u32 i; } c; c.i = ((u32)u) << 16; return c.f;
}
__device__ __forceinline__ u16 f2bf(float f) {
  union { float f; u32 i; } c; c.f = f;
  u32 u = c.i;
  u += 0x7fffu + ((u >> 16) & 1u);   // RNE
  return (u16)(u >> 16);
}

#define GLDS(gp, lp)                                                        \
  __builtin_amdgcn_global_load_lds(                                         \
      (__attribute__((address_space(1))) void*)(gp),                        \
      (__attribute__((address_space(3))) void*)(lp), 16, 0, 0)

// ---------------------------------------------------------------- prep: one launch for all pre-passes
__global__ __launch_bounds__(256) void prep(const float* __restrict__ x,
                                            const float* __restrict__ w1,
                                            const float* __restrict__ w2,
                                            const float* __restrict__ ww,
                                            u16* __restrict__ xbt,
                                            u16* __restrict__ w1b,
                                            u16* __restrict__ w2b,
                                            u16* __restrict__ wwb,
                                            u16* __restrict__ zreg)
{
  const int NX = (T_DIM * B_DIM * E_DIM) / 4;          // 8388608
  const int N1 = NX + (CD * E_DIM) / 4;                // +262144
  const int N2 = N1 + (E_DIM * CD) / 4;                // +262144
  const int N3 = N2 + (NH * KSZ * CD) / 4;             // +126976
  int i = blockIdx.x * 256 + threadIdx.x;
  if (i < NX) {
    int rr = i >> 8, c = i & 255;                      // row t*16+b, chunk within row
    int t = rr >> 4, b = rr & 15;
    fvec4 v = ((const fvec4*)x)[i];
    us4 o;
    o[0] = f2bf(v[0]); o[1] = f2bf(v[1]); o[2] = f2bf(v[2]); o[3] = f2bf(v[3]);
    ((us4*)xbt)[(size_t)(b * T_DIM + t) * 256 + c] = o;
  } else if (i < N1) {
    int j = i - NX;
    fvec4 v = ((const fvec4*)w1)[j];
    us4 o;
    o[0] = f2bf(v[0]); o[1] = f2bf(v[1]); o[2] = f2bf(v[2]); o[3] = f2bf(v[3]);
    ((us4*)w1b)[j] = o;
  } else if (i < N2) {
    int j = i - N1;
    fvec4 v = ((const fvec4*)w2)[j];
    us4 o;
    o[0] = f2bf(v[0]); o[1] = f2bf(v[1]); o[2] = f2bf(v[2]); o[3] = f2bf(v[3]);
    ((us4*)w2b)[j] = o;
  } else if (i < N3) {
    int j = i - N2;
    fvec4 v = ((const fvec4*)ww)[j];
    us4 o;
    o[0] = f2bf(v[0]); o[1] = f2bf(v[1]); o[2] = f2bf(v[2]); o[3] = f2bf(v[3]);
    ((us4*)wwb)[j] = o;
  } else {
    ((ui4*)zreg)[i - N3] = (ui4)(0u);
  }
}

// ---------------------------------------------------------------- 256x256 K-half-slot bf16 MFMA GEMM (B^T layout)
// BK=64 split into 2 K-halves of 32; 4 LDS slots per matrix (16 KB each), slot
// for (kt,kh) = (2kt+kh)&3. Phases per tile: p0{kh0,m0-3} p1{kh0,m4-7}
// p2{kh1,m0-3} p3{kh1,m4-7} — kh0 slot dies after p1 -> restaged 6 phases ahead.
// Stages: p0 -> (kt+1,kh1); p2 -> (kt+2,kh0). vmcnt(8) at p1/p3-end (never 0
// mid-loop), placed BEFORE the barrier (own-count -> barrier -> collective).
// Swizzle for 64B rows: u16col ^= ((row>>1)&3)<<3 (2-way banks, free).
template<int OUT_MODE, int GUARD_N, int A_CONV>
__global__ __launch_bounds__(512, 2) void gemm256(
    const u16* __restrict__ A, const u16* __restrict__ B,
    const float* __restrict__ bias, void* __restrict__ Cout,
    int N, int K, int ldc, int ntn)
{
  __shared__ u16 sA[4][256 * 32];    // 16 KB per slot
  __shared__ u16 sB[4][256 * 32];    // total 128 KB
  const int tid = threadIdx.x;
  const int lane = tid & 63;
  const int wid = tid >> 6;          // 0..7
  const int wr = wid >> 2;           // M half
  const int wc = wid & 3;            // N quarter

  const int swz = (blockIdx.x & 7) * (gridDim.x >> 3) + (blockIdx.x >> 3);
  const int bm = (swz / ntn) * 256;
  const int bn = (swz % ntn) * 256;

  // staging map: one GLDS covers 128 rows x 32 u16 (8 KB); 2 per matrix-half
  const int srow2 = tid >> 2;             // 0..127
  const int scol2 = (tid & 3) * 8;        // 0,8,16,24 (u16)
  const int scol2s = scol2 ^ (((srow2 >> 1) & 3) << 3);   // pre-swizzled source col
  const int sdst2 = srow2 * 32 + scol2;                    // linear LDS dest (u16)

  const u16* gA2[2];
  const u16* gB2[2];
  #pragma unroll
  for (int st = 0; st < 2; st++) {
    int rr = bm + st * 128 + srow2;
    if (A_CONV)
      gA2[st] = A + (size_t)(rr >> 11) * BSTRIDE + (size_t)(rr & 2047) * 64 + scol2s;
    else
      gA2[st] = A + (size_t)rr * K + scol2s;
    int br = bn + st * 128 + srow2;
    if (GUARD_N) br = min(br, N - 1);
    gB2[st] = B + (size_t)br * K + scol2s;
  }

  auto stage = [&](int kt, int kh) {
    int slot = (2 * kt + kh) & 3;
    size_t koA = A_CONV ? (size_t)kt * SLICE + kh * 32 : (size_t)kt * 64 + kh * 32;
    size_t koB = (size_t)kt * 64 + kh * 32;
    GLDS(gA2[0] + koA, &sA[slot][0 * 4096 + sdst2]);
    GLDS(gA2[1] + koA, &sA[slot][1 * 4096 + sdst2]);
    GLDS(gB2[0] + koB, &sB[slot][0 * 4096 + sdst2]);
    GLDS(gB2[1] + koB, &sB[slot][1 * 4096 + sdst2]);
  };

  f32x4 acc[8][4];
  #pragma unroll
  for (int i = 0; i < 8; i++)
    #pragma unroll
    for (int j = 0; j < 4; j++) acc[i][j] = (f32x4)(0.0f);

  const int fr = lane & 15;
  const int g8 = (lane >> 4) * 8;          // k-chunk (u16) within 32-k half

  // fragment read: row*32 + (g8 ^ ((row>>1)&3)<<3)
  auto ard = [&](const u16* base, int row) -> bf16x8 {
    return *(const bf16x8*)&base[row * 32 + (g8 ^ ((((row >> 1) & 3)) << 3))];
  };

  const int NT = K >> 6;

  // prologue: 3 halves staged; first half 8-deep behind
  stage(0, 0); stage(0, 1); stage(1, 0);
  asm volatile("s_waitcnt vmcnt(8)" ::: "memory");
  __builtin_amdgcn_s_barrier();

  for (int kt = 0; kt < NT; kt++) {
    const int s0 = (2 * kt) & 3;
    const int s1 = (2 * kt + 1) & 3;

    // ---------- p0: kh0, m0-3; stage (kt+1, kh1)
    bf16x8 bF[4], aG[4];
    #pragma unroll
    for (int n = 0; n < 4; n++) bF[n] = ard(&sB[s0][0], wc * 64 + n * 16 + fr);
    #pragma unroll
    for (int mi = 0; mi < 4; mi++) aG[mi] = ard(&sA[s0][0], wr * 128 + mi * 16 + fr);
    if (kt + 1 < NT) stage(kt + 1, 1);
    asm volatile("s_waitcnt lgkmcnt(0)" ::: "memory");
    __builtin_amdgcn_s_barrier();
    __builtin_amdgcn_sched_barrier(0);
    __builtin_amdgcn_s_setprio(1);
    #pragma unroll
    for (int mi = 0; mi < 4; mi++)
      #pragma unroll
      for (int n = 0; n < 4; n++)
        acc[mi][n] = __builtin_amdgcn_mfma_f32_16x16x32_bf16(aG[mi], bF[n], acc[mi][n], 0, 0, 0);
    __builtin_amdgcn_s_setprio(0);
    __builtin_amdgcn_sched_barrier(0);

    // ---------- p1: kh0, m4-7; vmcnt guards p2's kh1 slot
    #pragma unroll
    for (int mi = 0; mi < 4; mi++) aG[mi] = ard(&sA[s0][0], wr * 128 + (4 + mi) * 16 + fr);
    asm volatile("s_waitcnt lgkmcnt(0)" ::: "memory");
    if (kt < NT - 1) { asm volatile("s_waitcnt vmcnt(8)" ::: "memory"); }
    else             { asm volatile("s_waitcnt vmcnt(0)" ::: "memory"); }
    __builtin_amdgcn_s_barrier();
    __builtin_amdgcn_sched_barrier(0);
    __builtin_amdgcn_s_setprio(1);
    #pragma unroll
    for (int mi = 0; mi < 4; mi++)
      #pragma unroll
      for (int n = 0; n < 4; n++)
        acc[4 + mi][n] = __builtin_amdgcn_mfma_f32_16x16x32_bf16(aG[mi], bF[n], acc[4 + mi][n], 0, 0, 0);
    __builtin_amdgcn_s_setprio(0);
    __builtin_amdgcn_sched_barrier(0);

    // ---------- p2: kh1, m0-3; stage (kt+2, kh0)
    #pragma unroll
    for (int n = 0; n < 4; n++) bF[n] = ard(&sB[s1][0], wc * 64 + n * 16 + fr);
    #pragma unroll
    for (int mi = 0; mi < 4; mi++) aG[mi] = ard(&sA[s1][0], wr * 128 + mi * 16 + fr);
    if (kt + 2 < NT) stage(kt + 2, 0);
    asm volatile("s_waitcnt lgkmcnt(0)" ::: "memory");
    __builtin_amdgcn_s_barrier();
    __builtin_amdgcn_sched_barrier(0);
    __builtin_amdgcn_s_setprio(1);
    #pragma unroll
    for (int mi = 0; mi < 4; mi++)
      #pragma unroll
      for (int n = 0; n < 4; n++)
        acc[mi][n] = __builtin_amdgcn_mfma_f32_16x16x32_bf16(aG[mi], bF[n], acc[mi][n], 0, 0, 0);
    __builtin_amdgcn_s_setprio(0);
    __builtin_amdgcn_sched_barrier(0);

    // ---------- p3: kh1, m4-7; vmcnt guards next tile's kh0 slot
    #pragma unroll
    for (int mi = 0; mi < 4; mi++) aG[mi] = ard(&sA[s1][0], wr * 128 + (4 + mi) * 16 + fr);
    asm volatile("s_waitcnt lgkmcnt(0)" ::: "memory");
    if (kt < NT - 2)      { asm volatile("s_waitcnt vmcnt(8)" ::: "memory"); }
    else if (kt == NT - 2){ asm volatile("s_waitcnt vmcnt(4)" ::: "memory"); }
    __builtin_amdgcn_s_barrier();
    __builtin_amdgcn_sched_barrier(0);
    __builtin_amdgcn_s_setprio(1);
    #pragma unroll
    for (int mi = 0; mi < 4; mi++)
      #pragma unroll
      for (int n = 0; n < 4; n++)
        acc[4 + mi][n] = __builtin_amdgcn_mfma_f32_16x16x32_bf16(aG[mi], bF[n], acc[4 + mi][n], 0, 0, 0);
    __builtin_amdgcn_s_setprio(0);
    __builtin_amdgcn_sched_barrier(0);
  }

  const int orow0 = bm + wr * 128 + (lane >> 4) * 4;   // C/D: col=lane&15, row=(lane>>4)*4+q
  const int ocol0 = bn + wc * 64 + fr;
  #pragma unroll
  for (int m = 0; m < 8; m++) {
    #pragma unroll
    for (int n = 0; n < 4; n++) {
      #pragma unroll
      for (int q = 0; q < 4; q++) {
        int row = orow0 + m * 16 + q;
        int col = ocol0 + n * 16;
        if (!GUARD_N || col < N) {
          float v = acc[m][n][q] + bias[col];
          if (OUT_MODE == 1) {
            ((u16*)Cout)[(size_t)row * ldc + col] = f2bf(v);
          } else if (OUT_MODE == 2) {               // wt bf16 [b][h][t][32]
            int bb = row >> 11, t = row & 2047;
            int hh = col / 31, kk = col - hh * 31;  // compile-time magic div
            ((u16*)Cout)[((size_t)((bb * NH + hh) * T_DIM + t)) * 32 + kk] = f2bf(v);
          } else {                                  // 3: conv layout bf16
            int bb = row >> 11, t = row & 2047;
            ((u16*)Cout)[(size_t)((bb << 4) + (col >> 6)) * SLICE + (size_t)t * 64 + (col & 63)] = f2bf(v);
          }
        }
      }
    }
  }
}

// ---------------------------------------------------------------- dynamic conv + fused softmax (TT=128)
__global__ __launch_bounds__(256) void dconv(const u16* __restrict__ h1,
                                             const u16* __restrict__ wt,
                                             const u16* __restrict__ zreg,
                                             u16* __restrict__ outc)
{
  constexpr int TT = 128, HALO = 30, SW = 33;
  int bid = blockIdx.x;
  int tt = bid & 15;            // T/128 = 16
  int b  = (bid >> 4) & 15;
  int h  = bid >> 8;            // 0..15
  int s  = b * 16 + h;
  int t0 = tt * TT;
  __shared__ u16 hl[(TT + HALO) * 64];   // 19.75 KB
  __shared__ float wl[TT * SW];          // 16.5 KB
  int tid = threadIdx.x;

  const u16* slice = h1 + (size_t)s * SLICE;
  #pragma unroll
  for (int it = 0; it < 5; it++) {
    int c = it * 256 + tid;
    if (c < (TT + HALO) * 8) {
      int row = t0 - HALO + (c >> 3);
      const u16* src = slice + (size_t)row * 64 + (c & 7) * 8;
      if (row < 0) src = zreg + (c & 7) * 8;      // zeroed scratch
      GLDS(src, hl + c * 8);
    }
  }
  {
    const u16* wsrc = wt + ((size_t)s * T_DIM + t0) * 32;   // contiguous 8 KB bf16
    #pragma unroll
    for (int it = 0; it < 2; it++) {
      int j = (it * 256 + tid) * 8;
      us8 v = *(const us8*)(wsrc + j);
      int row = j >> 5, col = j & 31;
      #pragma unroll
      for (int e = 0; e < 8; e++) wl[row * SW + col + e] = bf2f(v[e]);
    }
  }
  __syncthreads();

  if (tid < TT) {
    float* p = wl + tid * SW;
    float v[KSZ];
    float mx = -1e30f;
    #pragma unroll
    for (int k = 0; k < KSZ; k++) { v[k] = p[k]; mx = fmaxf(mx, v[k]); }
    float sum = 0.f;
    #pragma unroll
    for (int k = 0; k < KSZ; k++) { v[k] = __expf(v[k] - mx); sum += v[k]; }
    float inv = 1.0f / sum;
    #pragma unroll
    for (int k = 0; k < KSZ; k++) p[k] = v[k] * inv;
  }
  __syncthreads();

  int rb = (tid & 7) * 8;           // channel sub-block
  int tl = tid >> 3;                // 0..31

  #pragma unroll
  for (int half = 0; half < 4; half++) {
    const int tb = tl + half * 32;
    const float* wp = wl + tb * SW;
    const u16* hb = hl + tb * 64 + rb;
    float acc[8];
    #pragma unroll
    for (int e = 0; e < 8; e++) acc[e] = 0.f;
    #pragma unroll
    for (int k = 0; k < KSZ; k++) {
      us8 hv = *(const us8*)(hb + k * 64);
      float w = wp[k];
      #pragma unroll
      for (int e = 0; e < 8; e++) acc[e] += w * bf2f(hv[e]);
    }
    us8 o;
    #pragma unroll
    for (int e = 0; e < 8; e++) o[e] = f2bf(acc[e]);
    *(us8*)(outc + (size_t)s * SLICE + (size_t)(t0 + tb) * 64 + rb) = o;
  }
}

// ---------------------------------------------------------------- residual + LayerNorm (bf16 x + bf16 h)
__global__ __launch_bounds__(256) void ln_res(const u16* __restrict__ xb,
                                              const u16* __restrict__ hb,
                                              float* __restrict__ out,
                                              const float* __restrict__ gamma,
                                              const float* __restrict__ beta)
{
  int mp = blockIdx.x;                 // b*2048 + t
  int b = mp >> 11, t = mp & 2047;
  int xrow = t * 16 + b;
  const us4* xr = (const us4*)(xb + (size_t)mp * E_DIM);
  const us4* hr = (const us4*)(hb + (size_t)mp * E_DIM);
  fvec4* yr = (fvec4*)(out + (size_t)xrow * E_DIM);
  int tid = threadIdx.x;
  us4 hv = hr[tid];
  us4 xv = xr[tid];
  fvec4 s;
  #pragma unroll
  for (int e = 0; e < 4; e++) s[e] = bf2f(xv[e]) + bf2f(hv[e]);
  float sum = s[0] + s[1] + s[2] + s[3];
  float sq  = s[0]*s[0] + s[1]*s[1] + s[2]*s[2] + s[3]*s[3];
  #pragma unroll
  for (int off = 32; off >= 1; off >>= 1) {
    sum += __shfl_xor(sum, off, 64);
    sq  += __shfl_xor(sq, off, 64);
  }
  __shared__ float red[8];
  int lane = tid & 63, wid = tid >> 6;
  if (lane == 0) { red[wid] = sum; red[4 + wid] = sq; }
  __syncthreads();
  sum = red[0] + red[1] + red[2] + red[3];
  sq  = red[4] + red[5] + red[6] + red[7];
  float mean = sum * (1.0f / E_DIM);
  float var  = sq * (1.0f / E_DIM) - mean * mean;
  float rstd = rsqrtf(var + 1e-5f);
  fvec4 g = ((const fvec4*)gamma)[tid];
  fvec4 be = ((const fvec4*)beta)[tid];
  fvec4 o;
  #pragma unroll
  for (int e = 0; e < 4; e++) o[e] = (s[e] - mean) * rstd * g[e] + be[e];
  yr[tid] = o;
}

// ---------------------------------------------------------------- launcher
extern "C" void kernel_launch(void* const* d_in, const int* in_sizes, int n_in,
                              void* d_out, int out_size, void* d_ws, size_t ws_size,
                              hipStream_t stream)
{
  const float* x     = (const float*)d_in[0];
  const float* w1    = (const float*)d_in[1];
  const float* b1    = (const float*)d_in[2];
  const float* ww    = (const float*)d_in[3];
  const float* bw    = (const float*)d_in[4];
  const float* w2    = (const float*)d_in[5];
  const float* b2    = (const float*)d_in[6];
  const float* gamma = (const float*)d_in[7];
  const float* beta  = (const float*)d_in[8];
  float* out = (float*)d_out;

  char* ws = (char*)d_ws;
  u16*   xbt  = (u16*)(ws);                          // 64 MB  xb'[b][t][e] (kept for ln_res)
  u16*   h1p  = (u16*)(ws + ((size_t)64 << 20));     // 64 MB  h1'[s][t][64]; reused as h2'
  u16*   wt   = (u16*)(ws + ((size_t)128 << 20));    // 32 MB  wt[b][h][t][32] bf16 logits
  u16*   convp = (u16*)(ws + ((size_t)160 << 20));   // 64 MB  conv'
  u16*   w1b  = (u16*)(ws + ((size_t)224 << 20));    // 2 MB
  u16*   w2b  = (u16*)(ws + ((size_t)226 << 20));    // 2 MB
  u16*   wwb  = (u16*)(ws + ((size_t)228 << 20));    // ~1 MB
  u16*   zreg = (u16*)(ws + ((size_t)230 << 20));    // 4 KB zeroed
  u16*   h2p  = h1p;                                 // h1p dead after dconv

  prep<<<35313, 256, 0, stream>>>(x, w1, w2, ww, xbt, w1b, w2b, wwb, zreg);

  // h1' = x @ w1^T + b1   (conv-layout bf16)
  gemm256<3, 0, 0><<<512, 512, 0, stream>>>(xbt, w1b, b1, h1p, CD, E_DIM, 0, 4);
  // wt[b][h][t][k] = h1' @ ww^T + bw   (bf16 logits, N=496 guarded)
  gemm256<2, 1, 1><<<256, 512, 0, stream>>>(h1p, wwb, bw, wt, NH * KSZ, CD, 0, 2);
  dconv<<<4096, 256, 0, stream>>>(h1p, wt, zreg, convp);
  // h2' = conv' @ w2^T + b2   (bf16, rows m')
  gemm256<1, 0, 1><<<512, 512, 0, stream>>>(convp, w2b, b2, h2p, E_DIM, CD, E_DIM, 4);
  ln_res<<<32768, 256, 0, stream>>>(xbt, h2p, out, gamma, beta);
}